// Round 1
// 177.641 us; speedup vs baseline: 1.0199x; 1.0199x over previous
//
#include <hip/hip_runtime.h>
#include <math.h>

#define D_MODEL 1024
#define D_FF    4096
#define RANK    128
#define M_ROWS  8192

typedef _Float16 f16;
typedef _Float16 f16x8 __attribute__((ext_vector_type(8)));
typedef float    f32x4 __attribute__((ext_vector_type(4)));

#define MFMA16(a, b, c) __builtin_amdgcn_mfma_f32_16x16x32_f16((a), (b), (c), 0, 0, 0)

__device__ __forceinline__ f16x8 ld8(const f16* p) { return *(const f16x8*)p; }

__device__ __forceinline__ f16x8 cvt8(float4 a0, float4 a1) {
    f16x8 r = { (f16)a0.x, (f16)a0.y, (f16)a0.z, (f16)a0.w,
                (f16)a1.x, (f16)a1.y, (f16)a1.z, (f16)a1.w };
    return r;
}

__device__ __forceinline__ float gelu_exact(float v) {
    return 0.5f * v * (1.0f + erff(v * 0.70710678118654752440f));
}

// ---------------------------------------------------------------------------
// Prep (verbatim-proven): convert/transpose/scale weights into ws (f16).
//  w1T[r][d]=cfcU[d][r]*cfcS[r] [128][1024] | v1[f][r]=cfcV [4096][128]
//  w2T[r][f]=pjU[f][r]*pjS[r]   [128][4096] | v2[d][r]=pjV  [1024][128]
// ---------------------------------------------------------------------------
__global__ __launch_bounds__(256) void k_prep(
    const float* __restrict__ cfcU, const float* __restrict__ cfcS,
    const float* __restrict__ cfcV, const float* __restrict__ pjU,
    const float* __restrict__ pjS,  const float* __restrict__ pjV,
    f16* __restrict__ w1T, f16* __restrict__ v1,
    f16* __restrict__ w2T, f16* __restrict__ v2)
{
    int i = blockIdx.x * 256 + threadIdx.x;
    if (i < 131072) {
        int r = i >> 10, d = i & 1023;
        w1T[i] = (f16)(cfcU[d * RANK + r] * cfcS[r]);
    } else if (i < 655360) {
        int j = i - 131072;
        v1[j] = (f16)cfcV[j];
    } else if (i < 1179648) {
        int j = i - 655360;
        int r = j >> 12, f = j & 4095;
        w2T[j] = (f16)(pjU[f * RANK + r] * pjS[r]);
    } else if (i < 1310720) {
        int j = i - 1179648;
        v2[j] = (f16)pjV[j];
    }
}

// ---------------------------------------------------------------------------
// Stage 1 v2: t1p[h][m][r] = x[m][K-half h] @ w1T^T, f16 partials.
// 512 thr = 8 waves (wm=wv&3: 4x16 m, wn=wv>>2: 2x64 r), BM=64.
// w1T K-half [128r][512k] staged ONCE into LDS (pad 520, one barrier total);
// x loaded direct global->reg, software-pipelined across kc (loads for kc+1
// issued under MFMA of kc). Grid (128 m-blocks, 2 halves) = 256 = 1/CU.
// ---------------------------------------------------------------------------
__global__ __launch_bounds__(512, 2) void k_t1(
    const float* __restrict__ x, const f16* __restrict__ w1T,
    f16* __restrict__ t1p)
{
    __shared__ __align__(16) f16 w1s[128 * 520];   // 133120 B

    const int tid  = threadIdx.x;
    const int lane = tid & 63;
    const int wv   = tid >> 6;
    const int wm   = wv & 3, wn = wv >> 2;
    const int m0b  = blockIdx.x * 64;
    const int h    = blockIdx.y;
    const int c    = lane & 15, q = lane >> 4;

#define LOADX(dst, kc)                                                          \
    _Pragma("unroll") for (int kb = 0; kb < 4; ++kb) {                          \
        const float* px = &x[(size_t)(m0b + wm * 16 + c) * D_MODEL +            \
                             h * 512 + (kc) * 128 + kb * 32 + q * 8];           \
        dst[kb][0] = *(const float4*)px;                                        \
        dst[kb][1] = *(const float4*)(px + 4); }

#define COMPUTEKC(src, kc)                                                      \
    _Pragma("unroll") for (int kb = 0; kb < 4; ++kb) {                          \
        f16x8 af = cvt8(src[kb][0], src[kb][1]);                                \
        _Pragma("unroll") for (int nt = 0; nt < 4; ++nt) {                      \
            f16x8 bf = *(const f16x8*)                                          \
                &w1s[(wn * 64 + nt * 16 + c) * 520 + (kc) * 128 + kb * 32 + q * 8]; \
            acc[nt] = MFMA16(af, bf, acc[nt]); } }

    float4 xa[4][2], xb[4][2];
    LOADX(xa, 0)                                   // issue earliest (HBM)

    // stage w1T K-half [128 r][512 k] once
#pragma unroll
    for (int i = 0; i < 16; ++i) {
        int id = i * 512 + tid;                    // < 8192 chunks of 8 f16
        int rr = id >> 6, k8 = id & 63;
        *(f16x8*)&w1s[rr * 520 + k8 * 8] =
            ld8(w1T + (size_t)rr * D_MODEL + h * 512 + k8 * 8);
    }
    __syncthreads();

    f32x4 acc[4] = {};
    LOADX(xb, 1)
    COMPUTEKC(xa, 0)
    LOADX(xa, 2)
    COMPUTEKC(xb, 1)
    LOADX(xb, 3)
    COMPUTEKC(xa, 2)
    COMPUTEKC(xb, 3)

    f16* o = t1p + (size_t)h * (M_ROWS * RANK);
#pragma unroll
    for (int nt = 0; nt < 4; ++nt)
#pragma unroll
        for (int i2 = 0; i2 < 4; ++i2)
            o[(size_t)(m0b + wm * 16 + q * 4 + i2) * RANK + wn * 64 + nt * 16 + c] =
                (f16)acc[nt][i2];
#undef LOADX
#undef COMPUTEKC
}

#define RED_STORE(buf, acc)                                            \
    _Pragma("unroll") for (int rt = 0; rt < 8; ++rt)                   \
    _Pragma("unroll") for (int i2 = 0; i2 < 4; ++i2)                   \
        (buf)[(q * 4 + i2) * 132 + rt * 16 + c] = (acc)[rt][i2];
#define RED_ADD(buf, acc)                                              \
    _Pragma("unroll") for (int rt = 0; rt < 8; ++rt)                   \
    _Pragma("unroll") for (int i2 = 0; i2 < 4; ++i2)                   \
        (acc)[rt][i2] += (buf)[(q * 4 + i2) * 132 + rt * 16 + c];

// ---------------------------------------------------------------------------
// Fused stages 2+3 v2: 512 thr = 8 waves (wm=wv&3: 4x16 m -> BM=64,
// wf=wv>>2: 2x64 f). Register-prefetch pipeline (distance 1, T14):
//   step(it): issue global loads tile it+1 -> nxt regs (overlaps everything)
//             barrier A (tile it-1 readers done)
//             ds_write cur regs -> LDS (vmcnt for cur: landed during it-1)
//             barrier B; compute tile it (stage2 -> gelu -> hs -> stage3)
// Single LDS buffer set: v1s[128][136] + w2s[128][136] + hs[8][16][72] = 88 KB.
// Grid 256 blocks = 1/CU, XCD-swizzled: each XCD owns one f-half s.
// ---------------------------------------------------------------------------
__device__ __forceinline__ void load_tiles(
    const f16* __restrict__ v1, const f16* __restrict__ w2T,
    int tid, int fb, f16x8 nv[4], f16x8 nw[4])
{
#pragma unroll
    for (int i = 0; i < 4; ++i) {
        int id = i * 512 + tid;                    // < 2048
        nv[i] = ld8(v1 + (size_t)(fb + (id >> 4)) * RANK + (id & 15) * 8);
    }
#pragma unroll
    for (int i = 0; i < 4; ++i) {
        int id = i * 512 + tid;
        nw[i] = ld8(w2T + (size_t)(id >> 4) * D_FF + fb + (id & 15) * 8);
    }
}

__device__ __forceinline__ void fused_step(
    const f16* __restrict__ v1, const f16* __restrict__ w2T,
    const float* __restrict__ bfc,
    f16* v1s, f16* w2s, f16* hs,
    const f16x8 a2[4], f32x4 c3[8],
    f16x8 cv[4], f16x8 cw[4], f16x8 nv[4], f16x8 nw[4],
    int tid, int s, int it, bool prefetch)
{
    const int lane = tid & 63;
    const int wv   = tid >> 6;
    const int wf   = wv >> 2;
    const int c    = lane & 15, q = lane >> 4;
    const int fbase = s * 2048 + it * 128;

    if (prefetch)
        load_tiles(v1, w2T, tid, fbase + 128, nv, nw);

    __syncthreads();                               // A: prev tile readers done
#pragma unroll
    for (int i = 0; i < 4; ++i) {
        int id = i * 512 + tid;
        *(f16x8*)&v1s[(id >> 4) * 136 + (id & 15) * 8] = cv[i];
    }
#pragma unroll
    for (int i = 0; i < 4; ++i) {
        int id = i * 512 + tid;
        *(f16x8*)&w2s[(id >> 4) * 136 + (id & 15) * 8] = cw[i];
    }
    __syncthreads();                               // B: tiles visible

    const int f0 = fbase + wf * 64;

    // ---- stage 2: h = t1 @ v1^T (4 f-tiles x K=128)
    f32x4 c2[4] = {};
#pragma unroll
    for (int nt = 0; nt < 4; ++nt)
#pragma unroll
        for (int kb = 0; kb < 4; ++kb) {
            f16x8 bf = *(const f16x8*)
                &v1s[(wf * 64 + nt * 16 + c) * 136 + kb * 32 + q * 8];
            c2[nt] = MFMA16(a2[kb], bf, c2[nt]);
        }

    // ---- bias + exact gelu -> per-wave hs (C-layout scatter)
#pragma unroll
    for (int nt = 0; nt < 4; ++nt) {
        float b = bfc[f0 + nt * 16 + c];
#pragma unroll
        for (int i2 = 0; i2 < 4; ++i2)
            hs[(wv * 16 + q * 4 + i2) * 72 + nt * 16 + c] =
                (f16)gelu_exact(c2[nt][i2] + b);
    }
    asm volatile("s_waitcnt lgkmcnt(0)" ::: "memory");  // wave-local RAW (proven)

    // ---- stage 3: t2 += h @ w2T^T
#pragma unroll
    for (int kb2 = 0; kb2 < 2; ++kb2) {
        f16x8 a3 = *(const f16x8*)&hs[(wv * 16 + c) * 72 + kb2 * 32 + q * 8];
#pragma unroll
        for (int rt = 0; rt < 8; ++rt) {
            f16x8 bf = *(const f16x8*)
                &w2s[(rt * 16 + c) * 136 + wf * 64 + kb2 * 32 + q * 8];
            c3[rt] = MFMA16(a3, bf, c3[rt]);
        }
    }
    asm volatile("s_waitcnt lgkmcnt(0)" ::: "memory");  // hs reused next iter
}

__global__ __launch_bounds__(512, 2) void k_fused(
    const f16* __restrict__ t1p, const f16* __restrict__ v1,
    const float* __restrict__ bfc, const f16* __restrict__ w2T,
    f16* __restrict__ t2p)
{
    __shared__ __align__(16) char smem[88064];
    f16*  v1s = (f16*)smem;                    // [128f][136r]  34816 B
    f16*  w2s = (f16*)(smem + 34816);          // [128r][136f]  34816 B
    f16*  hs  = (f16*)(smem + 69632);          // [8][16][72]   18432 B
    float* red = (float*)smem;                 // epilogue overlay on v1s

    const int tid  = threadIdx.x;
    const int lane = tid & 63;
    const int wv   = tid >> 6;
    const int wm   = wv & 3, wf = wv >> 2;
    const int c    = lane & 15, q = lane >> 4;

    // XCD swizzle: xcd = bx&7 (round-robin dispatch); XCDs 0-3 -> s=0, 4-7 -> s=1
    const int bx  = blockIdx.x;
    const int s   = (bx & 7) >> 2;
    const int mb  = (bx >> 3) * 4 + (bx & 3);  // bijective: 128 m-blocks per s
    const int m0b = mb * 64;

    // A2 fragments: sum of the two f16 t1 partials, re-rounded to f16
    f16x8 a2[4];
#pragma unroll
    for (int kb = 0; kb < 4; ++kb) {
        const size_t off = (size_t)(m0b + wm * 16 + c) * RANK + kb * 32 + q * 8;
        f16x8 p0 = ld8(t1p + off);
        f16x8 p1 = ld8(t1p + (size_t)(M_ROWS * RANK) + off);
#pragma unroll
        for (int e = 0; e < 8; ++e)
            a2[kb][e] = (f16)((float)p0[e] + (float)p1[e]);
    }

    f16x8 pv[4], pw[4], qv[4], qw[4];
    load_tiles(v1, w2T, tid, s * 2048, pv, pw);    // tile 0

    f32x4 c3[8] = {};
#pragma unroll 1
    for (int it = 0; it < 16; it += 2) {
        fused_step(v1, w2T, bfc, v1s, w2s, hs, a2, c3,
                   pv, pw, qv, qw, tid, s, it, true);
        fused_step(v1, w2T, bfc, v1s, w2s, hs, a2, c3,
                   qv, qw, pv, pw, tid, s, it + 1, it + 2 < 16);
    }

    // ---- 2-wave reduce over wf (proven pattern), write f16 partial t2p[s]
    __syncthreads();                           // done with v1s before overlay
    if (wf == 1) { RED_STORE(&red[wm * 16 * 132], c3) }
    __syncthreads();
    if (wf == 0) {
        RED_ADD(&red[wm * 16 * 132], c3)
        f16* o = t2p + (size_t)s * (M_ROWS * RANK);
#pragma unroll
        for (int rt = 0; rt < 8; ++rt)
#pragma unroll
            for (int i2 = 0; i2 < 4; ++i2)
                o[(size_t)(m0b + wm * 16 + q * 4 + i2) * RANK + rt * 16 + c] =
                    (f16)c3[rt][i2];
    }
}

// ---------------------------------------------------------------------------
// Stage 4 (unchanged): out = (t2p0+t2p1) @ v2^T + bpj, fp32 out.
// Block 256 thr = 4 waves (wm,wn): wave = 16m x 128n.
// Grid (256 m-tiles of 32, 4 n-tiles of 256) = 1024 blocks; LDS 69.6 KB.
// ---------------------------------------------------------------------------
__global__ __launch_bounds__(256, 2) void k_out(
    const f16* __restrict__ t2p, const f16* __restrict__ v2,
    const float* __restrict__ bpj, float* __restrict__ out)
{
    __shared__ __align__(16) f16 v2s[256 * 136];   // [256n][128k, pad 136]

    const int tid  = threadIdx.x;
    const int lane = tid & 63;
    const int wv   = tid >> 6;
    const int wm   = wv & 1, wn = wv >> 1;
    const int m0b  = blockIdx.x * 32;
    const int n0b  = blockIdx.y * 256;
    const int c    = lane & 15, q = lane >> 4;

    // stage v2 tile [256n][128k] once (K fully consumed)
#pragma unroll
    for (int i8 = 0; i8 < 16; ++i8) {
        int id = i8 * 256 + tid;               // < 4096
        int nn = id >> 4, k8 = id & 15;
        *(f16x8*)&v2s[nn * 136 + k8 * 8] =
            ld8(v2 + (size_t)(n0b + nn) * RANK + k8 * 8);
    }

    // A-frags: fp32 sum of the two f16 partials
    f16x8 a[4];
#pragma unroll
    for (int kb = 0; kb < 4; ++kb) {
        const size_t off = (size_t)(m0b + wm * 16 + c) * RANK + kb * 32 + q * 8;
        f16x8 p0 = ld8(t2p + off);
        f16x8 p1 = ld8(t2p + (size_t)(M_ROWS * RANK) + off);
#pragma unroll
        for (int e = 0; e < 8; ++e)
            a[kb][e] = (f16)((float)p0[e] + (float)p1[e]);
    }
    __syncthreads();

    f32x4 acc[8] = {};
#pragma unroll
    for (int nt = 0; nt < 8; ++nt)
#pragma unroll
        for (int kb = 0; kb < 4; ++kb) {
            f16x8 bf = *(const f16x8*)
                &v2s[(wn * 128 + nt * 16 + c) * 136 + kb * 32 + q * 8];
            acc[nt] = MFMA16(a[kb], bf, acc[nt]);
        }

#pragma unroll
    for (int nt = 0; nt < 8; ++nt) {
        float b = bpj[n0b + wn * 128 + nt * 16 + c];
#pragma unroll
        for (int i2 = 0; i2 < 4; ++i2)
            out[(size_t)(m0b + wm * 16 + q * 4 + i2) * D_MODEL +
                n0b + wn * 128 + nt * 16 + c] = acc[nt][i2] + b;
    }
}

extern "C" void kernel_launch(void* const* d_in, const int* in_sizes, int n_in,
                              void* d_out, int out_size, void* d_ws, size_t ws_size,
                              hipStream_t stream) {
    const float* x    = (const float*)d_in[0];
    const float* cfcU = (const float*)d_in[1];
    const float* cfcS = (const float*)d_in[2];
    const float* cfcV = (const float*)d_in[3];
    const float* cfcB = (const float*)d_in[4];
    const float* pjU  = (const float*)d_in[5];
    const float* pjS  = (const float*)d_in[6];
    const float* pjV  = (const float*)d_in[7];
    const float* pjB  = (const float*)d_in[8];
    float* out = (float*)d_out;

    // ws layout (f16 elements), 10.5 MB total (12 MB proven safe):
    f16* wsf = (f16*)d_ws;
    f16* t1p = wsf;                 // [2][8192*128]  4 MB
    f16* t2p = wsf + 2097152;       // [2][8192*128]  4 MB
    f16* w1T = wsf + 4194304;       // [128*1024]
    f16* v1  = w1T + 131072;        // [4096*128]
    f16* w2T = v1  + 524288;        // [128*4096]
    f16* v2  = w2T + 524288;        // [1024*128]

    k_prep <<<dim3(5120), 256, 0, stream>>>(cfcU, cfcS, cfcV, pjU, pjS, pjV,
                                            w1T, v1, w2T, v2);
    k_t1   <<<dim3(M_ROWS / 64, 2), 512, 0, stream>>>(x, w1T, t1p);
    k_fused<<<dim3(256), 512, 0, stream>>>(t1p, v1, cfcB, w2T, t2p);
    k_out  <<<dim3(M_ROWS / 32, D_MODEL / 256), 256, 0, stream>>>(t2p, v2, pjB, out);
}